// Round 1
// baseline (7839.024 us; speedup 1.0000x reference)
//
#include <hip/hip_runtime.h>
#include <hip/hip_fp16.h>

// ============================================================================
// LSTM_78176994722094: 2-layer LSTM (B=128, D_IN=128, T=1024, H=512) + fc head.
//
// R8: barrier-free per-wave pipeline. R7 forensics: 9.7K cycles/round were a
// serial chain [spin -> 32KB LDS staging -> barrier -> 8-way-conflicted
// ds_read_b128 (SQ_LDS_BANK_CONFLICT 1.34e8) -> MFMA -> L0 epi -> L1h -> L1
// epi -> barrier+vmcnt-drain -> one block flag], with both layers' publish
// behind a single flag and 2 block barriers amplifying stragglers.
//
// R8 changes (same proven L2-coherence discipline as R7):
//  1. B-fragments (h vectors) load DIRECTLY from the L2 exchange buffer with
//     agent-scope global_load_dwordx4 sc0 sc1 (fragment order == buffer
//     order). No hbuf, no staging, no LDS bank conflicts, NO __syncthreads
//     in the loop. Fence per rule: s_waitcnt vmcnt(0) + sched_barrier(0).
//  2. Per-WAVE flags, split per LAYER. flag0 set right after the L0 epilogue
//     (own vmcnt(0) drain, own flag) -> neighbors start round r+1 while this
//     wave still runs Wih1*h0, Whh1*h1 and the L1 epilogue. flag1 (set at
//     round end) has a full round of slack from the layer skew.
//  3. L0 critical chain split into 4 independent 8-deep MFMA accumulator
//     chains (hi/lo separate). x-refresh HBM load issued pre-spin, its
//     stores deferred past flag0.
//
// Everything else byte-equivalent to R7: same startup/claim/mode handshake,
// same exchange & xTw layouts, same split-precision weights (absmax 1.22e-4),
// same epilogues. Fallback (unbalanced placement) uses agent-scope stores on
// the same code path.
//
// Workspace (<4MB):
//   [0, 16KB)          sync: claim/mode/arrive + per-wave flags
//                        flag0: word 128  + c*128 + wcl   (8 clusters x 128)
//                        flag1: word 1280 + c*128 + wcl
//   [64KB, 576KB)      h exchange: [parity2][cluster8][layer2][b16][ch512] fp16
//   [640KB, 640KB+3MB) xTw: [slot3][cluster8][tau32][b16][d128] fp16
// ============================================================================

typedef _Float16 half8 __attribute__((ext_vector_type(8)));
typedef float f32x4 __attribute__((ext_vector_type(4)));
typedef unsigned long long u64;

#define MFMA16(a, b, c) __builtin_amdgcn_mfma_f32_16x16x32_f16((a), (b), (c), 0, 0, 0)

#define WS_EXCH_OFF (64 << 10)
#define WS_XTW_OFF (640 << 10)
// sync word indices (u32) within ws base
#define SYNC_CLAIM 0     // 8 u32
#define SYNC_MODE 16     // 1 u32 (0=undecided, 1=fallback, 2=local)
#define SYNC_ARRIVE 24   // 1 u32
#define SYNC_FLAG0 128   // 8 clusters x 128 u32 (per-wave, layer 0)
#define SYNC_FLAG1 1280  // 8 clusters x 128 u32 (per-wave, layer 1)

__device__ __forceinline__ float sigf(float x) {
  return __builtin_amdgcn_rcpf(1.f + exp2f(-1.44269504f * x));
}
__device__ __forceinline__ float tanhf_(float x) {
  return 1.f - 2.f * __builtin_amdgcn_rcpf(1.f + exp2f(2.88539008f * x));
}
__device__ __forceinline__ unsigned short f2h(float x) {
  _Float16 h = (_Float16)x;  // RNE
  unsigned short b;
  __builtin_memcpy(&b, &h, 2);
  return b;
}
__device__ __forceinline__ u64 lda(const u64* p) {
  return __hip_atomic_load(p, __ATOMIC_RELAXED, __HIP_MEMORY_SCOPE_AGENT);
}

// 16B agent-scope load (sc0 sc1 = bypass L1, probe the XCD L2). IMM is a
// literal byte offset. Result is NOT ready until VMFENCE(): the compiler does
// not track inline-asm loads in its waitcnt insertion, and register-only MFMA
// can be hoisted past a bare waitcnt -> sched_barrier(0) is mandatory.
#define LDF(dst, basep, IMM)                                             \
  asm volatile("global_load_dwordx4 %0, %1, off offset:" #IMM " sc0 sc1" \
               : "=&v"(dst)                                              \
               : "v"(basep)                                              \
               : "memory")
#define VMFENCE()                                    \
  do {                                               \
    asm volatile("s_waitcnt vmcnt(0)" ::: "memory"); \
    __builtin_amdgcn_sched_barrier(0);               \
  } while (0)

// split 8 fp32 weights -> hi fp16 + lo fp16 (lo = (w - hi) * 2^11)
__device__ __forceinline__ void cvt_split(const f32x4& a, const f32x4& b,
                                          half8& hi, half8& lo) {
#pragma unroll
  for (int i = 0; i < 4; ++i) {
    float w0 = a[i], w1 = b[i];
    _Float16 h0 = (_Float16)w0, h1 = (_Float16)w1;
    hi[i] = h0;
    hi[i + 4] = h1;
    lo[i] = (_Float16)((w0 - (float)h0) * 2048.0f);
    lo[i + 4] = (_Float16)((w1 - (float)h1) * 2048.0f);
  }
}
// scale a fragment by 2^-11 (exact exponent shift; v_pk_mul_f16)
__device__ __forceinline__ half8 hscale(half8 v) {
  half8 r;
#pragma unroll
  for (int i = 0; i < 8; ++i) r[i] = v[i] * (_Float16)4.8828125e-4f;
  return r;
}

// ---------------------------------------------------------------------------
// Prepass: fill xTw window 0 (t=0..31) slot 0, zero sync area (16KB) and out.
// ---------------------------------------------------------------------------
__global__ void __launch_bounds__(256) prep_kernel(const float* __restrict__ x,
                                                   _Float16* __restrict__ xTw,
                                                   unsigned* __restrict__ sync,
                                                   float* __restrict__ out) {
  const int bid = blockIdx.x;  // 128 = 8c * 16b
  const int c = bid >> 4, b16 = bid & 15;
  const int tid = threadIdx.x;
  if (bid == 0) {
#pragma unroll
    for (int i = 0; i < 16; ++i) sync[i * 256 + tid] = 0;  // 16KB sync area
    out[tid] = 0.f;  // out_size = B*OUT = 256
  }
  const int d = tid & 127, th = tid >> 7;  // th: tau half (0/1)
  const float* src = x + ((size_t)(c * 16 + b16) * 128 + d) * 1024 + th * 16;
  _Float16* dst = xTw + ((size_t)c * 32 + th * 16) * (16 * 128) + b16 * 128 + d;
#pragma unroll
  for (int i = 0; i < 16; ++i) dst[(size_t)i * (16 * 128)] = (_Float16)src[i];
}

// ---------------------------------------------------------------------------
// Persistent scan kernel. MFMA 16x16x32 f16 layouts (verified R1-R7):
//   A[m=lane&15][k=(lane>>4)*8+j], B[k][n=lane&15], D[m=(lane>>4)*4+reg][n].
// ---------------------------------------------------------------------------
__global__ void __launch_bounds__(256, 1) lstm_scan(
    const float* __restrict__ Whh0, const float* __restrict__ bih0,
    const float* __restrict__ bhh0, const float* __restrict__ Wih1,
    const float* __restrict__ Whh1, const float* __restrict__ bih1,
    const float* __restrict__ bhh1, const float* __restrict__ fcW,
    const float* __restrict__ fcb, const float* __restrict__ Wih0,
    const float* __restrict__ x, unsigned* __restrict__ sync,
    unsigned short* __restrict__ exch, _Float16* __restrict__ xTw,
    float* __restrict__ out) {
  __shared__ unsigned s_bcast[2];

  const int tid = threadIdx.x;
  const int wave = tid >> 6;
  const int lane = tid & 63;
  const int q = lane >> 4;
  const int bb = lane & 15;

  // ---- startup: XCD discovery + slot claim + grid barrier + mode decide ----
  unsigned xcc;
  asm("s_getreg_b32 %0, hwreg(HW_REG_XCC_ID)" : "=s"(xcc));
  xcc &= 7;
  unsigned* claim = sync + SYNC_CLAIM;
  unsigned* modew = sync + SYNC_MODE;
  unsigned* arrive = sync + SYNC_ARRIVE;
  if (tid == 0) {
    unsigned idx = __hip_atomic_fetch_add(claim + xcc, 1u, __ATOMIC_RELAXED,
                                          __HIP_MEMORY_SCOPE_AGENT);
    // (idx>>31)==0; data-dependency forces the claim RMW to complete first
    unsigned ord = __hip_atomic_fetch_add(arrive, 1u + (idx >> 31),
                                          __ATOMIC_RELAXED,
                                          __HIP_MEMORY_SCOPE_AGENT);
    if (ord == 255u) {  // last arriver decides for everyone
      unsigned ok = 1;
#pragma unroll
      for (int i = 0; i < 8; ++i)
        ok &= (__hip_atomic_load(claim + i, __ATOMIC_RELAXED,
                                 __HIP_MEMORY_SCOPE_AGENT) == 32u);
      __hip_atomic_store(modew, ok ? 2u : 1u, __ATOMIC_RELAXED,
                         __HIP_MEMORY_SCOPE_AGENT);
    }
    unsigned mv = 0;
    int guard = 0;
    for (;;) {
      mv = __hip_atomic_load(modew, __ATOMIC_RELAXED, __HIP_MEMORY_SCOPE_AGENT);
      if (mv != 0u) break;
      if (++guard > (1 << 18)) { mv = 1u; break; }
    }
    s_bcast[0] = mv;
    s_bcast[1] = idx;
  }
  __syncthreads();
  const bool loc = (s_bcast[0] == 2u);
  const int c = loc ? (int)xcc : (blockIdx.x >> 5);
  const int wg = loc ? (int)s_bcast[1] : (blockIdx.x & 31);

  const int wcl = wg * 4 + wave;  // wave id in cluster: 0..127
  const int chbase = wcl * 4;     // this wave's 4 hidden channels
  const int m = lane & 15;        // A-fragment row id for this lane
  const int arow = (m & 3) * 512 + chbase + (m >> 2);  // i,f,g,o gate order
  unsigned short* xtw16 = (unsigned short*)xTw;
  const u64* exch64c = (const u64*)exch;

  // ---- one-time: weight A-fragments (hi for all; lo for Whh0/Wih1/Wih0) ----
  half8 fW0[16], fW0lo[16], fW1i[16], fW1ilo[16], fW1h[16], fX[4], fXlo[4];
  {
    const float* p0 = Whh0 + (size_t)arow * 512 + q * 8;
    const float* p1 = Wih1 + (size_t)arow * 512 + q * 8;
    const float* p2 = Whh1 + (size_t)arow * 512 + q * 8;
#pragma unroll
    for (int kt = 0; kt < 16; ++kt) {
      f32x4 a0 = *(const f32x4*)(p0 + kt * 32), b0 = *(const f32x4*)(p0 + kt * 32 + 4);
      cvt_split(a0, b0, fW0[kt], fW0lo[kt]);
      f32x4 a1 = *(const f32x4*)(p1 + kt * 32), b1 = *(const f32x4*)(p1 + kt * 32 + 4);
      cvt_split(a1, b1, fW1i[kt], fW1ilo[kt]);
      f32x4 a2 = *(const f32x4*)(p2 + kt * 32), b2 = *(const f32x4*)(p2 + kt * 32 + 4);
      half8 dummy;
      cvt_split(a2, b2, fW1h[kt], dummy);  // hi only
    }
    const float* p3 = Wih0 + (size_t)arow * 128 + q * 8;
#pragma unroll
    for (int kt = 0; kt < 4; ++kt) {
      f32x4 a3 = *(const f32x4*)(p3 + kt * 32), b3 = *(const f32x4*)(p3 + kt * 32 + 4);
      cvt_split(a3, b3, fX[kt], fXlo[kt]);
    }
  }

  float b0v[4], b1v[4];
#pragma unroll
  for (int g = 0; g < 4; ++g) {
    int rrow = g * 512 + chbase + q;
    b0v[g] = bih0[rrow] + bhh0[rrow];
    b1v[g] = bih1[rrow] + bhh1[rrow];
  }
  const int ch = chbase + q;
  const float fcw0 = fcW[ch], fcw1 = fcW[512 + ch];

  unsigned* flag0 = sync + SYNC_FLAG0 + c * 128;
  unsigned* flag1 = sync + SYNC_FLAG1 + c * 128;
  const u64* spin0p = (const u64*)flag0 + lane;  // lane polls 2 wave-flags
  const u64* spin1p = (const u64*)flag1 + lane;

  float c0 = 0.f, c1 = 0.f;
  const int T = 1024;
  for (int r = 0; r <= T; ++r) {
    const bool L0 = (r < T);
    const bool L1 = (r > 0);
    const bool L1h = (r > 1);
    const bool doref = (wave == 2 && r < 992 && (r & 3) == 0);

    // ---- x refresh LOAD only (stores deferred past flag0). float4 read
    //      keeps HBM line amplification at 4x. ----
    f32x4 xv4;
    int sw = 0, rw = 0, xb = 0, xd = 0;
    if (doref) {
      const int wnext = (r >> 5) + 1;
      sw = wnext % 3; rw = r & 31;
      xb = wg >> 1; xd = (wg & 1) * 64 + lane;
      xv4 = *(const f32x4*)(x + ((size_t)(c * 16 + xb) * 128 + xd) * 1024 +
                            wnext * 32 + rw);
    }

    // ---- x fragments for t=r, issued BEFORE the spin (slot written >=32
    //      rounds ago -> long drained to the local L2) ----
    half8 xf[4];
    if (L0) {
      const int s = (r >> 5) % 3, tau = r & 31;
      const u64* xpq = (const u64*)xtw16 +
                       (((size_t)(s * 8 + c) * 32 + tau) * 16 + bb) * 32 + q * 2;
      LDF(xf[0], xpq, 0);
      LDF(xf[1], xpq, 64);
      LDF(xf[2], xpq, 128);
      LDF(xf[3], xpq, 192);
    }

    // ---- spin0: h0[r-1] published by all 128 waves of the cluster ----
    if (L1) {
      int guard = 0;
      for (;;) {
        u64 f = lda(spin0p);
        bool ok = ((unsigned)f >= (unsigned)r) &&
                  ((unsigned)(f >> 32) >= (unsigned)r);
        if (__ballot(ok) == ~0ull) break;
        if (++guard > 2048) break;  // diagnostic fail-fast, never hangs
      }
      asm volatile("" ::: "memory");  // keep fragment loads below the spin
    }

    // ---- h0[r-1] B-fragments, direct agent dwordx4 from the L2 exchange ----
    const int p = (r - 1) & 1;
    half8 hA[8], hB[8];
    if (L1) {
      const u64* h0p =
          exch64c + ((size_t)p * 8 + c) * 4096 + (size_t)bb * 128 + q * 2;
      LDF(hA[0], h0p, 0);   LDF(hB[0], h0p, 512);
      LDF(hA[1], h0p, 64);  LDF(hB[1], h0p, 576);
      LDF(hA[2], h0p, 128); LDF(hB[2], h0p, 640);
      LDF(hA[3], h0p, 192); LDF(hB[3], h0p, 704);
      LDF(hA[4], h0p, 256); LDF(hB[4], h0p, 768);
      LDF(hA[5], h0p, 320); LDF(hB[5], h0p, 832);
      LDF(hA[6], h0p, 384); LDF(hB[6], h0p, 896);
      LDF(hA[7], h0p, 448); LDF(hB[7], h0p, 960);
    }
    VMFENCE();  // xf + hA/hB ready (mandatory fence for inline-asm loads)

    // ---- L0 critical chain: 4 independent 8-deep MFMA chains + x chain ----
    if (L0) {
      f32x4 accX = {b0v[0], b0v[1], b0v[2], b0v[3]};
#pragma unroll
      for (int kt = 0; kt < 4; ++kt) {
        accX = MFMA16(fX[kt], xf[kt], accX);
        accX = MFMA16(fXlo[kt], hscale(xf[kt]), accX);
      }
      f32x4 a0 = {0.f, 0.f, 0.f, 0.f};
      f32x4 a0b = a0, a0l = a0, a0bl = a0;
      if (L1) {
#pragma unroll
        for (int kt = 0; kt < 8; ++kt) {
          a0 = MFMA16(fW0[kt], hA[kt], a0);
          a0b = MFMA16(fW0[kt + 8], hB[kt], a0b);
          a0l = MFMA16(fW0lo[kt], hscale(hA[kt]), a0l);
          a0bl = MFMA16(fW0lo[kt + 8], hscale(hB[kt]), a0bl);
        }
      }
      f32x4 g0 = accX + ((a0 + a0b) + (a0l + a0bl));
      float gi = sigf(g0.x), gf = sigf(g0.y), gg = tanhf_(g0.z), go = sigf(g0.w);
      c0 = gf * c0 + gi * gg;
      float h0v = go * tanhf_(c0);
      size_t idx = (((size_t)(r & 1) * 8 + c) * 32 + bb) * 512 + ch;
      if (loc)
        exch[idx] = f2h(h0v);  // plain -> dirty line in local L2
      else
        __hip_atomic_store(exch + idx, f2h(h0v), __ATOMIC_RELAXED,
                           __HIP_MEMORY_SCOPE_AGENT);
      asm volatile("s_waitcnt vmcnt(0)" ::: "memory");  // h0 store complete
      if (lane == 0) {
        if (loc)
          __hip_atomic_store(flag0 + wcl, (unsigned)(r + 1), __ATOMIC_RELAXED,
                             __HIP_MEMORY_SCOPE_WORKGROUP);
        else
          __hip_atomic_store(flag0 + wcl, (unsigned)(r + 1), __ATOMIC_RELAXED,
                             __HIP_MEMORY_SCOPE_AGENT);
      }
    }

    // ---- x refresh stores (off the h0 critical path) ----
    if (doref) {
#pragma unroll
      for (int j = 0; j < 4; ++j) {
        size_t xidx =
            (((size_t)(sw * 8 + c) * 32 + rw + j) * 16 + xb) * 128 + xd;
        if (loc)
          xtw16[xidx] = f2h(xv4[j]);
        else
          __hip_atomic_store(xtw16 + xidx, f2h(xv4[j]), __ATOMIC_RELAXED,
                             __HIP_MEMORY_SCOPE_AGENT);
      }
    }

    // ---- L1 input chain (Wih1 * h0[r-1]) -- after flag0, reuses hA/hB ----
    f32x4 a1 = {b1v[0], b1v[1], b1v[2], b1v[3]};
    f32x4 a1b = {0.f, 0.f, 0.f, 0.f};
    f32x4 a1c = a1b, a1d = a1b;
    if (L1) {
#pragma unroll
      for (int kt = 0; kt < 8; ++kt) {
        half8 hAs = hscale(hA[kt]), hBs = hscale(hB[kt]);
        a1 = MFMA16(fW1i[kt], hA[kt], a1);
        a1b = MFMA16(fW1i[kt + 8], hB[kt], a1b);
        a1 = MFMA16(fW1ilo[kt], hAs, a1);
        a1b = MFMA16(fW1ilo[kt + 8], hBs, a1b);
      }
    }

    // ---- L1 recurrent chain (Whh1 * h1[r-2]); flag1 has a round of slack ----
    if (L1h) {
      int guard = 0;
      for (;;) {
        u64 f = lda(spin1p);
        bool ok = ((unsigned)f >= (unsigned)r) &&
                  ((unsigned)(f >> 32) >= (unsigned)r);
        if (__ballot(ok) == ~0ull) break;
        if (++guard > 2048) break;
      }
      asm volatile("" ::: "memory");
      const u64* h1p = exch64c + ((size_t)p * 8 + c) * 4096 +
                       (size_t)(16 + bb) * 128 + q * 2;
      half8 hC[8], hD[8];
      LDF(hC[0], h1p, 0);   LDF(hD[0], h1p, 512);
      LDF(hC[1], h1p, 64);  LDF(hD[1], h1p, 576);
      LDF(hC[2], h1p, 128); LDF(hD[2], h1p, 640);
      LDF(hC[3], h1p, 192); LDF(hD[3], h1p, 704);
      LDF(hC[4], h1p, 256); LDF(hD[4], h1p, 768);
      LDF(hC[5], h1p, 320); LDF(hD[5], h1p, 832);
      LDF(hC[6], h1p, 384); LDF(hD[6], h1p, 896);
      LDF(hC[7], h1p, 448); LDF(hD[7], h1p, 960);
      VMFENCE();
#pragma unroll
      for (int kt = 0; kt < 8; ++kt) {
        a1c = MFMA16(fW1h[kt], hC[kt], a1c);
        a1d = MFMA16(fW1h[kt + 8], hD[kt], a1d);
      }
    }

    if (L1) {
      f32x4 g1 = (a1 + a1b) + (a1c + a1d);
      float gi = sigf(g1.x), gf = sigf(g1.y), gg = tanhf_(g1.z), go = sigf(g1.w);
      c1 = gf * c1 + gi * gg;
      float h1v = go * tanhf_(c1);
      if (r == T) {
        // fc head (out zeroed by prep_kernel each call)
        float s0 = h1v * fcw0, s1 = h1v * fcw1;
        s0 += __shfl_xor(s0, 16); s0 += __shfl_xor(s0, 32);
        s1 += __shfl_xor(s1, 16); s1 += __shfl_xor(s1, 32);
        if (q == 0) {
          atomicAdd(out + (size_t)(c * 16 + bb) * 2 + 0, s0);
          atomicAdd(out + (size_t)(c * 16 + bb) * 2 + 1, s1);
        }
        if (wcl == 0 && lane < 32)
          atomicAdd(out + (size_t)(c * 16 + (lane & 15)) * 2 + (lane >> 4),
                    fcb[lane >> 4]);
      } else {
        size_t idx = (((size_t)(r & 1) * 8 + c) * 32 + 16 + bb) * 512 + ch;
        if (loc)
          exch[idx] = f2h(h1v);
        else
          __hip_atomic_store(exch + idx, f2h(h1v), __ATOMIC_RELAXED,
                             __HIP_MEMORY_SCOPE_AGENT);
        asm volatile("s_waitcnt vmcnt(0)" ::: "memory");  // h1 store complete
        if (lane == 0) {
          if (loc)
            __hip_atomic_store(flag1 + wcl, (unsigned)(r + 1), __ATOMIC_RELAXED,
                               __HIP_MEMORY_SCOPE_WORKGROUP);
          else
            __hip_atomic_store(flag1 + wcl, (unsigned)(r + 1), __ATOMIC_RELAXED,
                               __HIP_MEMORY_SCOPE_AGENT);
        }
      }
    }
  }
}

extern "C" void kernel_launch(void* const* d_in, const int* in_sizes, int n_in,
                              void* d_out, int out_size, void* d_ws,
                              size_t ws_size, hipStream_t stream) {
  const float* x = (const float*)d_in[0];
  const float* Wih0 = (const float*)d_in[1];
  const float* Whh0 = (const float*)d_in[2];
  const float* bih0 = (const float*)d_in[3];
  const float* bhh0 = (const float*)d_in[4];
  const float* Wih1 = (const float*)d_in[5];
  const float* Whh1 = (const float*)d_in[6];
  const float* bih1 = (const float*)d_in[7];
  const float* bhh1 = (const float*)d_in[8];
  const float* fcW = (const float*)d_in[9];
  const float* fcb = (const float*)d_in[10];

  char* ws = (char*)d_ws;  // uses < 4MB total
  unsigned* sync = (unsigned*)ws;
  unsigned short* exch = (unsigned short*)(ws + WS_EXCH_OFF);
  _Float16* xTw = (_Float16*)(ws + WS_XTW_OFF);
  float* out = (float*)d_out;

  prep_kernel<<<dim3(128), dim3(256), 0, stream>>>(x, xTw, sync, out);
  lstm_scan<<<dim3(256), dim3(256), 0, stream>>>(Whh0, bih0, bhh0, Wih1, Whh1,
                                                 bih1, bhh1, fcW, fcb, Wih0, x,
                                                 sync, exch, xTw, out);
}